// Round 11
// baseline (403.193 us; speedup 1.0000x reference)
//
#include <hip/hip_runtime.h>
#include <cstddef>
#include <cstdint>

typedef unsigned short u16;
typedef __attribute__((ext_vector_type(8))) short bf16x8;
typedef __attribute__((ext_vector_type(8))) _Float16 f16x8;
typedef __attribute__((ext_vector_type(4))) float f32x4;
typedef __attribute__((ext_vector_type(16))) float f32x16;

#define GLOBAL_AS __attribute__((address_space(1)))
#define LDS_AS __attribute__((address_space(3)))

__device__ __forceinline__ void async16(const u16* g, u16* l) {
    __builtin_amdgcn_global_load_lds((GLOBAL_AS const uint32_t*)g,
                                     (LDS_AS uint32_t*)l, 16, 0, 0);
}

__device__ __forceinline__ u16 f2bf(float f) {
    uint32_t u = __builtin_bit_cast(uint32_t, f);
    uint32_t r = (u + 0x7FFFu + ((u >> 16) & 1u)) >> 16;
    return (u16)r;
}

// ---------------- fused weight prep (one kernel, 4 roles by blockIdx.z) ------------
__global__ __launch_bounds__(256)
void wprep(const float* __restrict__ WQ, const float* __restrict__ WK,
           const float* __restrict__ WV, const float* __restrict__ WO,
           u16* __restrict__ DQ, u16* __restrict__ DK,
           u16* __restrict__ DV, u16* __restrict__ DOb)
{
    const int role = blockIdx.z;
    __shared__ float t[32][33];
    int tx = threadIdx.x & 31, ty = threadIdx.x >> 5;
    int c0 = blockIdx.x * 32, r0 = blockIdx.y * 32;
    const float* S = role == 0 ? WQ : role == 1 ? WK : role == 2 ? WV : WO;

    if (role == 3) {
        #pragma unroll
        for (int k = 0; k < 4; ++k) {
            size_t o = (size_t)(r0 + ty + 8 * k) * 1024 + c0 + tx;
            DOb[o] = f2bf(S[o]);
        }
        return;
    }
    #pragma unroll
    for (int k = 0; k < 4; ++k)
        t[ty + 8 * k][tx] = S[(size_t)(r0 + ty + 8 * k) * 1024 + c0 + tx];
    __syncthreads();
    if (role == 2) {
        #pragma unroll
        for (int k = 0; k < 4; ++k)
            DV[(size_t)(c0 + ty + 8 * k) * 1024 + r0 + tx] = f2bf(t[tx][ty + 8 * k]);
    } else {
        u16* D = role == 0 ? DQ : DK;
        #pragma unroll
        for (int k = 0; k < 4; ++k) {
            float a = t[tx][ty + 8 * k] * 64.0f;
            _Float16 h0 = (_Float16)a;
            _Float16 h1 = (_Float16)(a - (float)h0);
            size_t o = (size_t)(c0 + ty + 8 * k) * 1024 + r0 + tx;
            D[o] = __builtin_bit_cast(u16, h0);
            D[1048576 + o] = __builtin_bit_cast(u16, h1);
        }
    }
}

// fused x-prep: fp32 x [1024, 2048] -> bf16 copy [1024,2048] AND transposed
// f16 2-plane x64 split [2048, 1024]
__global__ __launch_bounds__(256)
void xprep(const float* __restrict__ Sb, size_t sBatch,
           u16* __restrict__ BFb, size_t bfBatch,
           u16* __restrict__ Db, size_t dBatch, size_t plane)
{
    const float* S = Sb + blockIdx.z * sBatch;
    u16* BF = BFb + blockIdx.z * bfBatch;
    u16* D = Db + blockIdx.z * dBatch;
    __shared__ float t[32][33];
    int tx = threadIdx.x & 31, ty = threadIdx.x >> 5;
    int c0 = blockIdx.x * 32, r0 = blockIdx.y * 32;
    #pragma unroll
    for (int k = 0; k < 4; ++k) {
        float v = S[(size_t)(r0 + ty + 8 * k) * 2048 + c0 + tx];
        t[ty + 8 * k][tx] = v;
        BF[(size_t)(r0 + ty + 8 * k) * 2048 + c0 + tx] = f2bf(v);
    }
    __syncthreads();
    #pragma unroll
    for (int k = 0; k < 4; ++k) {
        float a = t[tx][ty + 8 * k] * 64.0f;
        _Float16 h0 = (_Float16)a;
        _Float16 h1 = (_Float16)(a - (float)h0);
        size_t o = (size_t)(c0 + ty + 8 * k) * 1024 + r0 + tx;
        D[o] = __builtin_bit_cast(u16, h0);
        D[plane + o] = __builtin_bit_cast(u16, h1);
    }
}

// ---------------- 128-tile 16x16 MFMA GEMM (weight prep, split-K over z) ----------
#define MMF4(AF, BF)                                                                   \
    _Pragma("unroll") for (int i = 0; i < 4; ++i)                                      \
        _Pragma("unroll") for (int j = 0; j < 4; ++j)                                  \
            acc[i][j] = __builtin_amdgcn_mfma_f32_16x16x32_f16(AF[i], BF[j], acc[i][j], 0, 0, 0);
#define MMB4(AF, BF)                                                                   \
    _Pragma("unroll") for (int i = 0; i < 4; ++i)                                      \
        _Pragma("unroll") for (int j = 0; j < 4; ++j)                                  \
            acc[i][j] = __builtin_amdgcn_mfma_f32_16x16x32_bf16(AF[i], BF[j], acc[i][j], 0, 0, 0);

template<int TERMS, int SPLITK>
__global__ __launch_bounds__(256)
void gemm_big(const u16* __restrict__ Ab, size_t aPlane,
              const u16* __restrict__ Bb, size_t bPlane,
              float* __restrict__ Cb, size_t cBatch,
              int M, int N, int K)
{
    constexpr int RSZ = 4096;
    constexpr int BUF = (TERMS == 3 ? 4 : 2) * RSZ;
    __shared__ u16 lds[2 * BUF];
    const u16* A = Ab;
    const u16* B = Bb;
    const int z = blockIdx.z;
    const int kt0 = SPLITK ? z * (K >> 2) : 0;
    const int kend = SPLITK ? kt0 + (K >> 2) : K;
    const int tid = threadIdx.x;
    const int lane = tid & 63, wave = tid >> 6;
    const int m0 = blockIdx.y * 128, n0 = blockIdx.x * 128;
    const int l15 = lane & 15, q = lane >> 4;
    const int rm = (wave >> 1) * 64, rn = (wave & 1) * 64;

    int sr[2], sg[2], sbase[2];
    #pragma unroll
    for (int it = 0; it < 2; ++it) {
        int s = tid + it * 256;
        sr[it] = s >> 2;
        sg[it] = (s & 3) ^ ((sr[it] >> 1) & 3);
        sbase[it] = (it * 256 + wave * 64) * 8;
    }
    const int fsw = (q ^ ((l15 >> 1) & 3)) * 8;
    int aoff[4], boff[4];
    #pragma unroll
    for (int f = 0; f < 4; ++f) {
        aoff[f] = (rm + f * 16 + l15) * 32 + fsw;
        boff[f] = (rn + f * 16 + l15) * 32 + fsw;
    }

    f32x4 acc[4][4];
    #pragma unroll
    for (int i = 0; i < 4; ++i)
        #pragma unroll
        for (int j = 0; j < 4; ++j)
            acc[i][j] = (f32x4){0.f, 0.f, 0.f, 0.f};

#define STAGEB(PP, KT)                                                                 \
    do {                                                                               \
        _Pragma("unroll")                                                              \
        for (int it = 0; it < 2; ++it) {                                               \
            const size_t ao = (size_t)(m0 + sr[it]) * K + (KT) + sg[it] * 8;           \
            const size_t bo = (size_t)(n0 + sr[it]) * K + (KT) + sg[it] * 8;           \
            const int d = (PP) * BUF + sbase[it];                                      \
            if (TERMS == 3) {                                                          \
                async16(A + ao, &lds[d]);                                              \
                async16(A + aPlane + ao, &lds[d + RSZ]);                               \
                async16(B + bo, &lds[d + 2 * RSZ]);                                    \
                async16(B + bPlane + bo, &lds[d + 3 * RSZ]);                           \
            } else {                                                                   \
                async16(A + ao, &lds[d]);                                              \
                async16(B + bo, &lds[d + RSZ]);                                       \
            }                                                                          \
        }                                                                              \
    } while (0)

    STAGEB(0, kt0);
    for (int kt = kt0; kt < kend; kt += 32) {
        const int p = (kt >> 5) & 1;
        __syncthreads();
        if (kt + 32 < kend) STAGEB(p ^ 1, kt + 32);
        const u16* L = &lds[p * BUF];
        if (TERMS == 3) {
            f16x8 a0f[4], b0f[4], xf[4];
            #pragma unroll
            for (int f = 0; f < 4; ++f) a0f[f] = *(const f16x8*)&L[aoff[f]];
            #pragma unroll
            for (int f = 0; f < 4; ++f) b0f[f] = *(const f16x8*)&L[2 * RSZ + boff[f]];
            MMF4(a0f, b0f);
            #pragma unroll
            for (int f = 0; f < 4; ++f) xf[f] = *(const f16x8*)&L[3 * RSZ + boff[f]];
            MMF4(a0f, xf);
            #pragma unroll
            for (int f = 0; f < 4; ++f) xf[f] = *(const f16x8*)&L[RSZ + aoff[f]];
            MMF4(xf, b0f);
        } else {
            bf16x8 af[4], bf_[4];
            #pragma unroll
            for (int f = 0; f < 4; ++f) af[f] = *(const bf16x8*)&L[aoff[f]];
            #pragma unroll
            for (int f = 0; f < 4; ++f) bf_[f] = *(const bf16x8*)&L[RSZ + boff[f]];
            MMB4(af, bf_);
        }
    }
#undef STAGEB

    float* C = Cb + (size_t)z * cBatch;
    #pragma unroll
    for (int i = 0; i < 4; ++i) {
        int row = m0 + rm + i * 16 + q * 4;
        #pragma unroll
        for (int j = 0; j < 4; ++j) {
            int col = n0 + rn + j * 16 + l15;
            #pragma unroll
            for (int r = 0; r < 4; ++r)
                C[(size_t)(row + r) * N + col] = acc[i][j][r];
        }
    }
}

// merged reduction: y=0 -> sum P1 planes, f16-2split*2^-12 into M2;
//                   y=1 -> sum P2 planes, bf16 into WOV.
__global__ __launch_bounds__(256)
void reduce4b(const float4* __restrict__ P1, const float4* __restrict__ P2,
              u16* __restrict__ M2, u16* __restrict__ WOV)
{
    size_t i = blockIdx.x * 256 + threadIdx.x;
    const float4* P = blockIdx.y == 0 ? P1 : P2;
    float4 a = P[i], b = P[262144 + i], c = P[524288 + i], d = P[786432 + i];
    float v[4] = { a.x + b.x + c.x + d.x, a.y + b.y + c.y + d.y,
                   a.z + b.z + c.z + d.z, a.w + b.w + c.w + d.w };
    if (blockIdx.y == 0) {
        #pragma unroll
        for (int k = 0; k < 4; ++k) {
            float vs = v[k] * 0.000244140625f;
            _Float16 h0 = (_Float16)vs;
            _Float16 h1 = (_Float16)(vs - (float)h0);
            M2[i * 4 + k] = __builtin_bit_cast(u16, h0);
            M2[1048576 + i * 4 + k] = __builtin_bit_cast(u16, h1);
        }
    } else {
        ushort4 o = { f2bf(v[0]), f2bf(v[1]), f2bf(v[2]), f2bf(v[3]) };
        *(ushort4*)&WOV[i * 4] = o;
    }
}

// shared fragment-read / MFMA macros for the split GEMM (LDS layout: A0|A1|B0|B1)
#define RDAF(dst, PL, H)                                                               \
    _Pragma("unroll")                                                                  \
    for (int f = 0; f < FM; ++f)                                                       \
        dst[f] = *(const f16x8*)&L[(PL) * ASZ + arow[f] * 32 + ((2 * (H) + half) ^ asw[f]) * 8];
#define RDBF(dst, PL, H)                                                               \
    _Pragma("unroll")                                                                  \
    for (int f = 0; f < FN; ++f)                                                       \
        dst[f] = *(const f16x8*)&L[2 * ASZ + (PL) * BSZ + brow[f] * 32 + ((2 * (H) + half) ^ bsw[f]) * 8];
#define MMW(AF, BF)                                                                    \
    _Pragma("unroll")                                                                  \
    for (int i = 0; i < FM; ++i)                                                       \
        _Pragma("unroll")                                                              \
        for (int j = 0; j < FN; ++j)                                                   \
            acc[i][j] = __builtin_amdgcn_mfma_f32_32x32x16_f16(AF[i], BF[j], acc[i][j], 0, 0, 0);
#define MMWB(AF, BF)                                                                   \
    _Pragma("unroll")                                                                  \
    for (int i = 0; i < FM; ++i)                                                       \
        _Pragma("unroll")                                                              \
        for (int j = 0; j < FN; ++j)                                                   \
            acc[i][j] = __builtin_amdgcn_mfma_f32_32x32x16_bf16(AF[i], BF[j], acc[i][j], 0, 0, 0);

// ---------------- wide-tile 32x32x16 MFMA GEMM (512 thr, dyn LDS, dbuf) ----------------
// TERMS=3: f16 2-plane split, 3 terms (register-pipelined). TERMS=1: bf16.
// EPI: 0 fp32, 1 f16-2split*2^-12, 2 bf16.
// STATS=1 (used by the S^T gemm): epilogue additionally emits per-column softmax
// partials (max, sum-exp) over this block's 128-row bands into
// statsOut[z*16 + grp][col], grp = by*WGM + wave/WGN. Lanes l and l+32 share a
// column (col = ...+l31) and are merged via shfl_xor(32); half==0 lanes store.
template<int TERMS, int EPI, int TM, int TN, int WGM, int WGN, int STATS>
__global__ __launch_bounds__(512, 2)
void gemm_w(const u16* __restrict__ Ab, size_t aBatch, size_t aPlane,
            const u16* __restrict__ Bb, size_t bBatch, size_t bPlane,
            void* __restrict__ Cb, size_t cBatch, size_t cPlane,
            int M, int N, int K, float2* __restrict__ statsOut)
{
    constexpr int ASZ = TM * 32;
    constexpr int BSZ = TN * 32;
    constexpr int APL = (TERMS == 3) ? 2 : 1;
    constexpr int BUF = APL * (ASZ + BSZ);
    constexpr int FM = TM / WGM / 32;
    constexpr int FN = TN / WGN / 32;
    constexpr int AIT = TM / 128;
    constexpr int BIT = TN / 128;
    extern __shared__ __align__(16) u16 lds[];

    int bid = blockIdx.x + gridDim.x * blockIdx.y;
    int cpr = gridDim.x >> 2;
    int c8 = bid & 7, kk = bid >> 3;
    int bx = (kk % cpr) * 4 + (c8 & 3);
    int by = (kk / cpr) * 2 + (c8 >> 2);

    const u16* A = Ab + blockIdx.z * aBatch;
    const u16* B = Bb + blockIdx.z * bBatch;
    const int tid = threadIdx.x;
    const int lane = tid & 63, wave = tid >> 6;
    const int m0 = by * TM, n0 = bx * TN;
    const int l31 = lane & 31, half = lane >> 5;
    const int rm = (wave / WGN) * (TM / WGM);
    const int rn = (wave % WGN) * (TN / WGN);

    int arow[FM], asw[FM], brow[FN], bsw[FN];
    #pragma unroll
    for (int f = 0; f < FM; ++f) { arow[f] = rm + f * 32 + l31; asw[f] = (arow[f] >> 1) & 3; }
    #pragma unroll
    for (int f = 0; f < FN; ++f) { brow[f] = rn + f * 32 + l31; bsw[f] = (brow[f] >> 1) & 3; }

    f32x16 acc[FM][FN];
    #pragma unroll
    for (int i = 0; i < FM; ++i)
        #pragma unroll
        for (int j = 0; j < FN; ++j)
            #pragma unroll
            for (int r = 0; r < 16; ++r) acc[i][j][r] = 0.f;

    auto stage = [&](int pp, int kt) {
        #pragma unroll
        for (int it = 0; it < AIT; ++it) {
            int s = tid + it * 512;
            int r = s >> 2;
            int g = (s & 3) ^ ((r >> 1) & 3);
            int base = pp * BUF + (it * 512 + wave * 64) * 8;
            size_t go = (size_t)(m0 + r) * K + kt + g * 8;
            async16(A + go, &lds[base]);
            if (TERMS == 3) async16(A + aPlane + go, &lds[base + ASZ]);
        }
        #pragma unroll
        for (int it = 0; it < BIT; ++it) {
            int s = tid + it * 512;
            int r = s >> 2;
            int g = (s & 3) ^ ((r >> 1) & 3);
            int base = pp * BUF + APL * ASZ + (it * 512 + wave * 64) * 8;
            size_t go = (size_t)(n0 + r) * K + kt + g * 8;
            async16(B + go, &lds[base]);
            if (TERMS == 3) async16(B + bPlane + go, &lds[base + BSZ]);
        }
    };

    stage(0, 0);
    for (int kt = 0; kt < K; kt += 32) {
        const int p = (kt >> 5) & 1;
        __syncthreads();
        if (kt + 32 < K) stage(p ^ 1, kt + 32);
        const u16* L = &lds[p * BUF];
        if (TERMS == 3) {
            f16x8 A0h0[FM], A0h1[FM], B0h0[FN], B0h1[FN];
            f16x8 B1h0[FN], B1h1[FN], A1h0[FM], A1h1[FM];
            RDAF(A0h0, 0, 0) RDBF(B0h0, 0, 0)
            RDAF(A0h1, 0, 1) RDBF(B0h1, 0, 1)
            RDBF(B1h0, 1, 0)
            MMW(A0h0, B0h0)
            RDBF(B1h1, 1, 1)
            MMW(A0h1, B0h1)
            RDAF(A1h0, 1, 0)
            MMW(A0h0, B1h0)
            MMW(A0h1, B1h1)
            RDAF(A1h1, 1, 1)
            MMW(A1h0, B0h0)
            MMW(A1h1, B0h1)
        } else {
            bf16x8 Ah0[FM], Ah1[FM], Bh0[FN], Bh1[FN];
            #pragma unroll
            for (int f = 0; f < FM; ++f)
                Ah0[f] = *(const bf16x8*)&L[arow[f] * 32 + (half ^ asw[f]) * 8];
            #pragma unroll
            for (int f = 0; f < FN; ++f)
                Bh0[f] = *(const bf16x8*)&L[ASZ + brow[f] * 32 + (half ^ bsw[f]) * 8];
            #pragma unroll
            for (int f = 0; f < FM; ++f)
                Ah1[f] = *(const bf16x8*)&L[arow[f] * 32 + ((2 + half) ^ asw[f]) * 8];
            #pragma unroll
            for (int f = 0; f < FN; ++f)
                Bh1[f] = *(const bf16x8*)&L[ASZ + brow[f] * 32 + ((2 + half) ^ bsw[f]) * 8];
            MMWB(Ah0, Bh0)
            MMWB(Ah1, Bh1)
        }
    }

    if constexpr (STATS) {
        #pragma unroll
        for (int j = 0; j < FN; ++j) {
            float mx = -3.4e38f;
            #pragma unroll
            for (int i = 0; i < FM; ++i)
                #pragma unroll
                for (int r = 0; r < 16; ++r) mx = fmaxf(mx, acc[i][j][r]);
            float se = 0.f;
            #pragma unroll
            for (int i = 0; i < FM; ++i)
                #pragma unroll
                for (int r = 0; r < 16; ++r) se += __expf(acc[i][j][r] - mx);
            float mo = __shfl_xor(mx, 32, 64);
            float so = __shfl_xor(se, 32, 64);
            float mM = fmaxf(mx, mo);
            float sS = se * __expf(mx - mM) + so * __expf(mo - mM);
            if (half == 0) {
                int col = n0 + rn + j * 32 + l31;
                int grp = by * WGM + (wave / WGN);
                statsOut[((size_t)blockIdx.z * 16 + grp) * 2048 + col] = (float2){mM, sS};
            }
        }
    }

    #pragma unroll
    for (int i = 0; i < FM; ++i) {
        #pragma unroll
        for (int j = 0; j < FN; ++j) {
            int col = n0 + rn + j * 32 + l31;
            #pragma unroll
            for (int r = 0; r < 16; ++r) {
                int row = m0 + rm + i * 32 + (r & 3) + 8 * (r >> 2) + 4 * half;
                float v = acc[i][j][r];
                size_t o = (size_t)row * N + col;
                if (EPI == 0) {
                    ((float*)Cb + blockIdx.z * cBatch)[o] = v;
                } else if (EPI == 1) {
                    u16* C0 = (u16*)Cb + blockIdx.z * cBatch;
                    float vs = v * 0.000244140625f;
                    _Float16 h0 = (_Float16)vs;
                    _Float16 h1 = (_Float16)(vs - (float)h0);
                    C0[o] = __builtin_bit_cast(u16, h0);
                    C0[cPlane + o] = __builtin_bit_cast(u16, h1);
                } else {
                    ((u16*)Cb + blockIdx.z * cBatch)[o] = f2bf(v);
                }
            }
        }
    }
}

#undef RDAF
#undef RDBF
#undef MMW
#undef MMWB

// ---------------- texp: PT[j,i] = bf16( exp(ST[j,i]-M_i) / S_i ) ----------------
// Elementwise over ST (already transposed: S-gemm writes S^T). Combines the 16
// per-band stats partials online in registers (8 cols/thread), then streams 16
// rows per block with float4 reads / ushort4 writes. Grid (128, G), 256 thr.
__global__ __launch_bounds__(256)
void texp(const float* __restrict__ STb, size_t sBatch,
          const float2* __restrict__ SG, u16* __restrict__ PTb, size_t pBatch)
{
    const float* ST = STb + blockIdx.y * sBatch;
    u16* PT = PTb + blockIdx.y * pBatch;
    const float2* st = SG + (size_t)blockIdx.y * 16 * 2048;
    const int t = threadIdx.x;

    float Mv[8], Rv[8];
    #pragma unroll
    for (int e = 0; e < 8; ++e) {
        int col = (e < 4) ? (4 * t + e) : (1024 + 4 * t + (e - 4));
        float M = -3.4e38f, S = 0.f;
        #pragma unroll
        for (int g = 0; g < 16; ++g) {
            float2 p = st[g * 2048 + col];
            if (p.x > M) { S = S * __expf(M - p.x) + p.y; M = p.x; }
            else         { S += p.y * __expf(p.x - M); }
        }
        Mv[e] = M;
        Rv[e] = 1.0f / S;
    }

    const int j0 = blockIdx.x * 16;
    for (int jr = 0; jr < 16; ++jr) {
        const float* row = ST + (size_t)(j0 + jr) * 2048;
        u16* prow = PT + (size_t)(j0 + jr) * 2048;
        float4 v0 = *(const float4*)&row[4 * t];
        float4 v1 = *(const float4*)&row[1024 + 4 * t];
        ushort4 o0 = { f2bf(__expf(v0.x - Mv[0]) * Rv[0]),
                       f2bf(__expf(v0.y - Mv[1]) * Rv[1]),
                       f2bf(__expf(v0.z - Mv[2]) * Rv[2]),
                       f2bf(__expf(v0.w - Mv[3]) * Rv[3]) };
        ushort4 o1 = { f2bf(__expf(v1.x - Mv[4]) * Rv[4]),
                       f2bf(__expf(v1.y - Mv[5]) * Rv[5]),
                       f2bf(__expf(v1.z - Mv[6]) * Rv[6]),
                       f2bf(__expf(v1.w - Mv[7]) * Rv[7]) };
        *(ushort4*)&prow[4 * t] = o0;
        *(ushort4*)&prow[1024 + 4 * t] = o1;
    }
}

// ---------------- driver ----------------
extern "C" void kernel_launch(void* const* d_in, const int* in_sizes, int n_in,
                              void* d_out, int out_size, void* d_ws, size_t ws_size,
                              hipStream_t stream)
{
    const size_t MB = 1048576;
    const size_t WREG = 34 * MB;
    const size_t PER  = 32 * MB;
    const size_t PER_US = PER / 2, PER_F = PER / 4;

    char* ws = (char*)d_ws;
    u16* WQT2 = (u16*)ws;
    u16* WKT2 = (u16*)(ws + 4 * MB);
    u16* M2   = (u16*)(ws + 8 * MB);
    u16* WObf = (u16*)(ws + 12 * MB);
    u16* WVT  = (u16*)(ws + 14 * MB);
    u16* WOV  = (u16*)(ws + 16 * MB);
    u16* xbf  = (u16*)(ws + 18 * MB);
    // softmax stats [G][16][2048] float2 = 1 MB, over WQT2/WKT2 (dead after gemm_big #1)
    float2* STATSG = (float2*)ws;

    int G = (ws_size >= WREG + 4 * PER) ? 4 : (ws_size >= WREG + 2 * PER) ? 2 : 1;

    const float* x = (const float*)d_in[0];
    float* out = (float*)d_out;
    dim3 blk(256);

    hipFuncSetAttribute((const void*)gemm_w<3, 0, 256, 256, 2, 4, 1>,
                        hipFuncAttributeMaxDynamicSharedMemorySize, 131072);
    hipFuncSetAttribute((const void*)gemm_w<3, 1, 256, 128, 4, 2, 0>,
                        hipFuncAttributeMaxDynamicSharedMemorySize, 98304);

    // ---- weight prep (once): fused elementwise + split-K GEMMs, merged reduce ----
    float* PART1 = (float*)(ws + WREG);            // 16 MB fp32 partials
    float* PART2 = (float*)(ws + WREG + 16 * MB);  // 16 MB fp32 partials
    wprep<<<dim3(32, 32, 4), blk, 0, stream>>>(
        (const float*)d_in[1], (const float*)d_in[2],
        (const float*)d_in[3], (const float*)d_in[4],
        WQT2, WKT2, WVT, WObf);
    gemm_big<3, 1><<<dim3(8, 8, 4), blk, 0, stream>>>(WKT2, 1048576, WQT2, 1048576,
                                                      PART1, 1048576, 1024, 1024, 1024);
    gemm_big<1, 1><<<dim3(8, 8, 4), blk, 0, stream>>>(WObf, 0, WVT, 0,
                                                      PART2, 1048576, 1024, 1024, 1024);
    reduce4b<<<dim3(1024, 2), blk, 0, stream>>>((const float4*)PART1, (const float4*)PART2,
                                                M2, WOV);

    for (int b0 = 0; b0 < 4; b0 += G) {
        char* R = ws + WREG;
        u16*   xT2 = (u16*)R;               // [i,d] 64x f16-split, plane 2097152 u16
        u16*   TT2 = (u16*)(R + 8 * MB);    // [j,d] split(T/64)
        float* ST  = (float*)(R + 16 * MB); // fp32 S^T [j,i]
        u16*   PTb = (u16*)(R + 8 * MB);    // bf16 P^T [j,i] (over dead TT2)
        u16*   XPT = (u16*)R;               // bf16 [j,d'] (over dead xT2)

        // x -> xbf (bf16 copy) + xT2 (transposed 64x f16 2-plane), one pass
        xprep<<<dim3(64, 32, G), blk, 0, stream>>>(x + (size_t)b0 * 2097152, 2097152,
                                                   xbf + (size_t)b0 * 2097152, 2097152,
                                                   xT2, PER_US, 2097152);
        // T^T = (64x)^T M: [j,d] f16-split out
        gemm_w<3, 1, 256, 128, 4, 2, 0><<<dim3(8, 8, G), 512, 98304, stream>>>(
            xT2, PER_US, 2097152, M2, 0, 1048576, TT2, PER_US, 2097152,
            2048, 1024, 1024, nullptr);
        // ST[j,i] = (T/64)[j,:] . (64x)[i,:]  (operand swap -> writes S^T)
        // + per-column softmax partials into STATSG
        gemm_w<3, 0, 256, 256, 2, 4, 1><<<dim3(8, 8, G), 512, 131072, stream>>>(
            TT2, PER_US, 2097152, xT2, PER_US, 2097152, ST, PER_F, 0,
            2048, 2048, 1024, STATSG);
        // PT[j,i] = bf16 softmax (elementwise on ST; combines stats inline)
        texp<<<dim3(128, G), blk, 0, stream>>>(ST, PER_F, STATSG, PTb, PER_US);
        // XPT[j,d'] = PT[j,:] . xbf[d',:]  (XPT over dead xT2)
        gemm_w<1, 2, 256, 128, 4, 2, 0><<<dim3(8, 8, G), 512, 49152, stream>>>(
            PTb, PER_US, 0, xbf + (size_t)b0 * 2097152, 2097152, 0,
            XPT, PER_US, 0, 2048, 1024, 2048, nullptr);
        // out[d,j] = WOV[d,:] . XPT[j,:]
        gemm_w<1, 0, 256, 128, 4, 2, 0><<<dim3(16, 4, G), 512, 49152, stream>>>(
            WOV, 0, 0, XPT, PER_US, 0, out + (size_t)b0 * 2097152, 2097152, 0,
            1024, 2048, 1024, nullptr);
    }
}

// Round 12
// 381.068 us; speedup vs baseline: 1.0581x; 1.0581x over previous
//
#include <hip/hip_runtime.h>
#include <cstddef>
#include <cstdint>

typedef unsigned short u16;
typedef __attribute__((ext_vector_type(8))) short bf16x8;
typedef __attribute__((ext_vector_type(8))) _Float16 f16x8;
typedef __attribute__((ext_vector_type(4))) float f32x4;
typedef __attribute__((ext_vector_type(16))) float f32x16;

#define GLOBAL_AS __attribute__((address_space(1)))
#define LDS_AS __attribute__((address_space(3)))

__device__ __forceinline__ void async16(const u16* g, u16* l) {
    __builtin_amdgcn_global_load_lds((GLOBAL_AS const uint32_t*)g,
                                     (LDS_AS uint32_t*)l, 16, 0, 0);
}

__device__ __forceinline__ u16 f2bf(float f) {
    uint32_t u = __builtin_bit_cast(uint32_t, f);
    uint32_t r = (u + 0x7FFFu + ((u >> 16) & 1u)) >> 16;
    return (u16)r;
}

// ---------------- fused weight prep (one kernel, 4 roles by blockIdx.z) ------------
__global__ __launch_bounds__(256)
void wprep(const float* __restrict__ WQ, const float* __restrict__ WK,
           const float* __restrict__ WV, const float* __restrict__ WO,
           u16* __restrict__ DQ, u16* __restrict__ DK,
           u16* __restrict__ DV, u16* __restrict__ DOb)
{
    const int role = blockIdx.z;
    __shared__ float t[32][33];
    int tx = threadIdx.x & 31, ty = threadIdx.x >> 5;
    int c0 = blockIdx.x * 32, r0 = blockIdx.y * 32;
    const float* S = role == 0 ? WQ : role == 1 ? WK : role == 2 ? WV : WO;

    if (role == 3) {
        #pragma unroll
        for (int k = 0; k < 4; ++k) {
            size_t o = (size_t)(r0 + ty + 8 * k) * 1024 + c0 + tx;
            DOb[o] = f2bf(S[o]);
        }
        return;
    }
    #pragma unroll
    for (int k = 0; k < 4; ++k)
        t[ty + 8 * k][tx] = S[(size_t)(r0 + ty + 8 * k) * 1024 + c0 + tx];
    __syncthreads();
    if (role == 2) {
        #pragma unroll
        for (int k = 0; k < 4; ++k)
            DV[(size_t)(c0 + ty + 8 * k) * 1024 + r0 + tx] = f2bf(t[tx][ty + 8 * k]);
    } else {
        u16* D = role == 0 ? DQ : DK;
        #pragma unroll
        for (int k = 0; k < 4; ++k) {
            float a = t[tx][ty + 8 * k] * 64.0f;
            _Float16 h0 = (_Float16)a;
            _Float16 h1 = (_Float16)(a - (float)h0);
            size_t o = (size_t)(c0 + ty + 8 * k) * 1024 + r0 + tx;
            D[o] = __builtin_bit_cast(u16, h0);
            D[1048576 + o] = __builtin_bit_cast(u16, h1);
        }
    }
}

// fused x-prep: fp32 x [1024, 2048] -> bf16 copy [1024,2048] AND transposed
// f16 2-plane x64 split [2048, 1024]
__global__ __launch_bounds__(256)
void xprep(const float* __restrict__ Sb, size_t sBatch,
           u16* __restrict__ BFb, size_t bfBatch,
           u16* __restrict__ Db, size_t dBatch, size_t plane)
{
    const float* S = Sb + blockIdx.z * sBatch;
    u16* BF = BFb + blockIdx.z * bfBatch;
    u16* D = Db + blockIdx.z * dBatch;
    __shared__ float t[32][33];
    int tx = threadIdx.x & 31, ty = threadIdx.x >> 5;
    int c0 = blockIdx.x * 32, r0 = blockIdx.y * 32;
    #pragma unroll
    for (int k = 0; k < 4; ++k) {
        float v = S[(size_t)(r0 + ty + 8 * k) * 2048 + c0 + tx];
        t[ty + 8 * k][tx] = v;
        BF[(size_t)(r0 + ty + 8 * k) * 2048 + c0 + tx] = f2bf(v);
    }
    __syncthreads();
    #pragma unroll
    for (int k = 0; k < 4; ++k) {
        float a = t[tx][ty + 8 * k] * 64.0f;
        _Float16 h0 = (_Float16)a;
        _Float16 h1 = (_Float16)(a - (float)h0);
        size_t o = (size_t)(c0 + ty + 8 * k) * 1024 + r0 + tx;
        D[o] = __builtin_bit_cast(u16, h0);
        D[plane + o] = __builtin_bit_cast(u16, h1);
    }
}

// ---------------- 128-tile 16x16 MFMA GEMM (weight prep, split-K over z) ----------
#define MMF4(AF, BF)                                                                   \
    _Pragma("unroll") for (int i = 0; i < 4; ++i)                                      \
        _Pragma("unroll") for (int j = 0; j < 4; ++j)                                  \
            acc[i][j] = __builtin_amdgcn_mfma_f32_16x16x32_f16(AF[i], BF[j], acc[i][j], 0, 0, 0);
#define MMB4(AF, BF)                                                                   \
    _Pragma("unroll") for (int i = 0; i < 4; ++i)                                      \
        _Pragma("unroll") for (int j = 0; j < 4; ++j)                                  \
            acc[i][j] = __builtin_amdgcn_mfma_f32_16x16x32_bf16(AF[i], BF[j], acc[i][j], 0, 0, 0);

template<int TERMS, int SPLITK>
__global__ __launch_bounds__(256)
void gemm_big(const u16* __restrict__ Ab, size_t aPlane,
              const u16* __restrict__ Bb, size_t bPlane,
              float* __restrict__ Cb, size_t cBatch,
              int M, int N, int K)
{
    constexpr int RSZ = 4096;
    constexpr int BUF = (TERMS == 3 ? 4 : 2) * RSZ;
    __shared__ u16 lds[2 * BUF];
    const u16* A = Ab;
    const u16* B = Bb;
    const int z = blockIdx.z;
    const int kt0 = SPLITK ? z * (K >> 2) : 0;
    const int kend = SPLITK ? kt0 + (K >> 2) : K;
    const int tid = threadIdx.x;
    const int lane = tid & 63, wave = tid >> 6;
    const int m0 = blockIdx.y * 128, n0 = blockIdx.x * 128;
    const int l15 = lane & 15, q = lane >> 4;
    const int rm = (wave >> 1) * 64, rn = (wave & 1) * 64;

    int sr[2], sg[2], sbase[2];
    #pragma unroll
    for (int it = 0; it < 2; ++it) {
        int s = tid + it * 256;
        sr[it] = s >> 2;
        sg[it] = (s & 3) ^ ((sr[it] >> 1) & 3);
        sbase[it] = (it * 256 + wave * 64) * 8;
    }
    const int fsw = (q ^ ((l15 >> 1) & 3)) * 8;
    int aoff[4], boff[4];
    #pragma unroll
    for (int f = 0; f < 4; ++f) {
        aoff[f] = (rm + f * 16 + l15) * 32 + fsw;
        boff[f] = (rn + f * 16 + l15) * 32 + fsw;
    }

    f32x4 acc[4][4];
    #pragma unroll
    for (int i = 0; i < 4; ++i)
        #pragma unroll
        for (int j = 0; j < 4; ++j)
            acc[i][j] = (f32x4){0.f, 0.f, 0.f, 0.f};

#define STAGEB(PP, KT)                                                                 \
    do {                                                                               \
        _Pragma("unroll")                                                              \
        for (int it = 0; it < 2; ++it) {                                               \
            const size_t ao = (size_t)(m0 + sr[it]) * K + (KT) + sg[it] * 8;           \
            const size_t bo = (size_t)(n0 + sr[it]) * K + (KT) + sg[it] * 8;           \
            const int d = (PP) * BUF + sbase[it];                                      \
            if (TERMS == 3) {                                                          \
                async16(A + ao, &lds[d]);                                              \
                async16(A + aPlane + ao, &lds[d + RSZ]);                               \
                async16(B + bo, &lds[d + 2 * RSZ]);                                    \
                async16(B + bPlane + bo, &lds[d + 3 * RSZ]);                           \
            } else {                                                                   \
                async16(A + ao, &lds[d]);                                              \
                async16(B + bo, &lds[d + RSZ]);                                       \
            }                                                                          \
        }                                                                              \
    } while (0)

    STAGEB(0, kt0);
    for (int kt = kt0; kt < kend; kt += 32) {
        const int p = (kt >> 5) & 1;
        __syncthreads();
        if (kt + 32 < kend) STAGEB(p ^ 1, kt + 32);
        const u16* L = &lds[p * BUF];
        if (TERMS == 3) {
            f16x8 a0f[4], b0f[4], xf[4];
            #pragma unroll
            for (int f = 0; f < 4; ++f) a0f[f] = *(const f16x8*)&L[aoff[f]];
            #pragma unroll
            for (int f = 0; f < 4; ++f) b0f[f] = *(const f16x8*)&L[2 * RSZ + boff[f]];
            MMF4(a0f, b0f);
            #pragma unroll
            for (int f = 0; f < 4; ++f) xf[f] = *(const f16x8*)&L[3 * RSZ + boff[f]];
            MMF4(a0f, xf);
            #pragma unroll
            for (int f = 0; f < 4; ++f) xf[f] = *(const f16x8*)&L[RSZ + aoff[f]];
            MMF4(xf, b0f);
        } else {
            bf16x8 af[4], bf_[4];
            #pragma unroll
            for (int f = 0; f < 4; ++f) af[f] = *(const bf16x8*)&L[aoff[f]];
            #pragma unroll
            for (int f = 0; f < 4; ++f) bf_[f] = *(const bf16x8*)&L[RSZ + boff[f]];
            MMB4(af, bf_);
        }
    }
#undef STAGEB

    float* C = Cb + (size_t)z * cBatch;
    #pragma unroll
    for (int i = 0; i < 4; ++i) {
        int row = m0 + rm + i * 16 + q * 4;
        #pragma unroll
        for (int j = 0; j < 4; ++j) {
            int col = n0 + rn + j * 16 + l15;
            #pragma unroll
            for (int r = 0; r < 4; ++r)
                C[(size_t)(row + r) * N + col] = acc[i][j][r];
        }
    }
}

// merged reduction: y=0 -> sum P1 planes, f16-2split*2^-12 into M2;
//                   y=1 -> sum P2 planes, bf16 into WOV.
__global__ __launch_bounds__(256)
void reduce4b(const float4* __restrict__ P1, const float4* __restrict__ P2,
              u16* __restrict__ M2, u16* __restrict__ WOV)
{
    size_t i = blockIdx.x * 256 + threadIdx.x;
    const float4* P = blockIdx.y == 0 ? P1 : P2;
    float4 a = P[i], b = P[262144 + i], c = P[524288 + i], d = P[786432 + i];
    float v[4] = { a.x + b.x + c.x + d.x, a.y + b.y + c.y + d.y,
                   a.z + b.z + c.z + d.z, a.w + b.w + c.w + d.w };
    if (blockIdx.y == 0) {
        #pragma unroll
        for (int k = 0; k < 4; ++k) {
            float vs = v[k] * 0.000244140625f;
            _Float16 h0 = (_Float16)vs;
            _Float16 h1 = (_Float16)(vs - (float)h0);
            M2[i * 4 + k] = __builtin_bit_cast(u16, h0);
            M2[1048576 + i * 4 + k] = __builtin_bit_cast(u16, h1);
        }
    } else {
        ushort4 o = { f2bf(v[0]), f2bf(v[1]), f2bf(v[2]), f2bf(v[3]) };
        *(ushort4*)&WOV[i * 4] = o;
    }
}

// shared fragment-read / MFMA macros for the split GEMM (LDS layout: A0|A1|B0|B1)
#define RDAF(dst, PL, H)                                                               \
    _Pragma("unroll")                                                                  \
    for (int f = 0; f < FM; ++f)                                                       \
        dst[f] = *(const f16x8*)&L[(PL) * ASZ + arow[f] * 32 + ((2 * (H) + half) ^ asw[f]) * 8];
#define RDBF(dst, PL, H)                                                               \
    _Pragma("unroll")                                                                  \
    for (int f = 0; f < FN; ++f)                                                       \
        dst[f] = *(const f16x8*)&L[2 * ASZ + (PL) * BSZ + brow[f] * 32 + ((2 * (H) + half) ^ bsw[f]) * 8];
#define MMW(AF, BF)                                                                    \
    _Pragma("unroll")                                                                  \
    for (int i = 0; i < FM; ++i)                                                       \
        _Pragma("unroll")                                                              \
        for (int j = 0; j < FN; ++j)                                                   \
            acc[i][j] = __builtin_amdgcn_mfma_f32_32x32x16_f16(AF[i], BF[j], acc[i][j], 0, 0, 0);
#define MMWB(AF, BF)                                                                   \
    _Pragma("unroll")                                                                  \
    for (int i = 0; i < FM; ++i)                                                       \
        _Pragma("unroll")                                                              \
        for (int j = 0; j < FN; ++j)                                                   \
            acc[i][j] = __builtin_amdgcn_mfma_f32_32x32x16_bf16(AF[i], BF[j], acc[i][j], 0, 0, 0);

// ---------------- wide-tile 32x32x16 MFMA GEMM (512 thr, dyn LDS, dbuf) ----------------
// TERMS=3: f16 2-plane split, 3 terms (register-pipelined). TERMS=1: bf16.
// EPI: 0 fp32, 1 f16-2split*2^-12, 2 bf16.
// STATS=1 (S^T gemm): epilogue emits per-column softmax partials (max, sum-exp)
// over this block's 128-row bands into statsOut[z*16 + grp][col].
template<int TERMS, int EPI, int TM, int TN, int WGM, int WGN, int STATS>
__global__ __launch_bounds__(512, 2)
void gemm_w(const u16* __restrict__ Ab, size_t aBatch, size_t aPlane,
            const u16* __restrict__ Bb, size_t bBatch, size_t bPlane,
            void* __restrict__ Cb, size_t cBatch, size_t cPlane,
            int M, int N, int K, float2* __restrict__ statsOut)
{
    constexpr int ASZ = TM * 32;
    constexpr int BSZ = TN * 32;
    constexpr int APL = (TERMS == 3) ? 2 : 1;
    constexpr int BUF = APL * (ASZ + BSZ);
    constexpr int FM = TM / WGM / 32;
    constexpr int FN = TN / WGN / 32;
    constexpr int AIT = TM / 128;
    constexpr int BIT = TN / 128;
    extern __shared__ __align__(16) u16 lds[];

    int bid = blockIdx.x + gridDim.x * blockIdx.y;
    int cpr = gridDim.x >> 2;
    int c8 = bid & 7, kk = bid >> 3;
    int bx = (kk % cpr) * 4 + (c8 & 3);
    int by = (kk / cpr) * 2 + (c8 >> 2);

    const u16* A = Ab + blockIdx.z * aBatch;
    const u16* B = Bb + blockIdx.z * bBatch;
    const int tid = threadIdx.x;
    const int lane = tid & 63, wave = tid >> 6;
    const int m0 = by * TM, n0 = bx * TN;
    const int l31 = lane & 31, half = lane >> 5;
    const int rm = (wave / WGN) * (TM / WGM);
    const int rn = (wave % WGN) * (TN / WGN);

    int arow[FM], asw[FM], brow[FN], bsw[FN];
    #pragma unroll
    for (int f = 0; f < FM; ++f) { arow[f] = rm + f * 32 + l31; asw[f] = (arow[f] >> 1) & 3; }
    #pragma unroll
    for (int f = 0; f < FN; ++f) { brow[f] = rn + f * 32 + l31; bsw[f] = (brow[f] >> 1) & 3; }

    f32x16 acc[FM][FN];
    #pragma unroll
    for (int i = 0; i < FM; ++i)
        #pragma unroll
        for (int j = 0; j < FN; ++j)
            #pragma unroll
            for (int r = 0; r < 16; ++r) acc[i][j][r] = 0.f;

    auto stage = [&](int pp, int kt) {
        #pragma unroll
        for (int it = 0; it < AIT; ++it) {
            int s = tid + it * 512;
            int r = s >> 2;
            int g = (s & 3) ^ ((r >> 1) & 3);
            int base = pp * BUF + (it * 512 + wave * 64) * 8;
            size_t go = (size_t)(m0 + r) * K + kt + g * 8;
            async16(A + go, &lds[base]);
            if (TERMS == 3) async16(A + aPlane + go, &lds[base + ASZ]);
        }
        #pragma unroll
        for (int it = 0; it < BIT; ++it) {
            int s = tid + it * 512;
            int r = s >> 2;
            int g = (s & 3) ^ ((r >> 1) & 3);
            int base = pp * BUF + APL * ASZ + (it * 512 + wave * 64) * 8;
            size_t go = (size_t)(n0 + r) * K + kt + g * 8;
            async16(B + go, &lds[base]);
            if (TERMS == 3) async16(B + bPlane + go, &lds[base + BSZ]);
        }
    };

    stage(0, 0);
    for (int kt = 0; kt < K; kt += 32) {
        const int p = (kt >> 5) & 1;
        __syncthreads();
        if (kt + 32 < K) stage(p ^ 1, kt + 32);
        const u16* L = &lds[p * BUF];
        if (TERMS == 3) {
            f16x8 A0h0[FM], A0h1[FM], B0h0[FN], B0h1[FN];
            f16x8 B1h0[FN], B1h1[FN], A1h0[FM], A1h1[FM];
            RDAF(A0h0, 0, 0) RDBF(B0h0, 0, 0)
            RDAF(A0h1, 0, 1) RDBF(B0h1, 0, 1)
            RDBF(B1h0, 1, 0)
            MMW(A0h0, B0h0)
            RDBF(B1h1, 1, 1)
            MMW(A0h1, B0h1)
            RDAF(A1h0, 1, 0)
            MMW(A0h0, B1h0)
            MMW(A0h1, B1h1)
            RDAF(A1h1, 1, 1)
            MMW(A1h0, B0h0)
            MMW(A1h1, B0h1)
        } else {
            bf16x8 Ah0[FM], Ah1[FM], Bh0[FN], Bh1[FN];
            #pragma unroll
            for (int f = 0; f < FM; ++f)
                Ah0[f] = *(const bf16x8*)&L[arow[f] * 32 + (half ^ asw[f]) * 8];
            #pragma unroll
            for (int f = 0; f < FN; ++f)
                Bh0[f] = *(const bf16x8*)&L[ASZ + brow[f] * 32 + (half ^ bsw[f]) * 8];
            #pragma unroll
            for (int f = 0; f < FM; ++f)
                Ah1[f] = *(const bf16x8*)&L[arow[f] * 32 + ((2 + half) ^ asw[f]) * 8];
            #pragma unroll
            for (int f = 0; f < FN; ++f)
                Bh1[f] = *(const bf16x8*)&L[ASZ + brow[f] * 32 + ((2 + half) ^ bsw[f]) * 8];
            MMWB(Ah0, Bh0)
            MMWB(Ah1, Bh1)
        }
    }

    if constexpr (STATS) {
        #pragma unroll
        for (int j = 0; j < FN; ++j) {
            float mx = -3.4e38f;
            #pragma unroll
            for (int i = 0; i < FM; ++i)
                #pragma unroll
                for (int r = 0; r < 16; ++r) mx = fmaxf(mx, acc[i][j][r]);
            float se = 0.f;
            #pragma unroll
            for (int i = 0; i < FM; ++i)
                #pragma unroll
                for (int r = 0; r < 16; ++r) se += __expf(acc[i][j][r] - mx);
            float mo = __shfl_xor(mx, 32, 64);
            float so = __shfl_xor(se, 32, 64);
            float mM = fmaxf(mx, mo);
            float sS = se * __expf(mx - mM) + so * __expf(mo - mM);
            if (half == 0) {
                int col = n0 + rn + j * 32 + l31;
                int grp = by * WGM + (wave / WGN);
                statsOut[((size_t)blockIdx.z * 16 + grp) * 2048 + col] = (float2){mM, sS};
            }
        }
    }

    #pragma unroll
    for (int i = 0; i < FM; ++i) {
        #pragma unroll
        for (int j = 0; j < FN; ++j) {
            int col = n0 + rn + j * 32 + l31;
            #pragma unroll
            for (int r = 0; r < 16; ++r) {
                int row = m0 + rm + i * 32 + (r & 3) + 8 * (r >> 2) + 4 * half;
                float v = acc[i][j][r];
                size_t o = (size_t)row * N + col;
                if (EPI == 0) {
                    ((float*)Cb + blockIdx.z * cBatch)[o] = v;
                } else if (EPI == 1) {
                    u16* C0 = (u16*)Cb + blockIdx.z * cBatch;
                    float vs = v * 0.000244140625f;
                    _Float16 h0 = (_Float16)vs;
                    _Float16 h1 = (_Float16)(vs - (float)h0);
                    C0[o] = __builtin_bit_cast(u16, h0);
                    C0[cPlane + o] = __builtin_bit_cast(u16, h1);
                } else {
                    ((u16*)Cb + blockIdx.z * cBatch)[o] = f2bf(v);
                }
            }
        }
    }
}

#undef RDAF
#undef RDBF
#undef MMW
#undef MMWB

// ---------------- statsred: combine 16 per-band partials -> final (M, 1/S) per col ----
__global__ __launch_bounds__(256)
void statsred(const float2* __restrict__ SG, float2* __restrict__ SF)
{
    int col = blockIdx.x * 256 + threadIdx.x;          // grid (8, G)
    const float2* st = SG + (size_t)blockIdx.y * 16 * 2048;
    float M = -3.4e38f, S = 0.f;
    #pragma unroll
    for (int g = 0; g < 16; ++g) {
        float2 p = st[g * 2048 + col];
        if (p.x > M) { S = S * __expf(M - p.x) + p.y; M = p.x; }
        else         { S += p.y * __expf(p.x - M); }
    }
    SF[(size_t)blockIdx.y * 2048 + col] = (float2){M, 1.0f / S};
}

// ---------------- texp (parallel): PT[j,i] = bf16( exp(ST[j,i]-M_i) * R_i ) ----------
// One ST row per block (grid (2048, G)), 256 thr x 8 elems — softmax_p's proven
// fully-parallel shape. Stats are pre-combined finals (L2-hot 16KB/batch).
__global__ __launch_bounds__(256)
void texp(const float* __restrict__ STb, size_t sBatch,
          const float2* __restrict__ SF, u16* __restrict__ PTb, size_t pBatch)
{
    const float* row = STb + blockIdx.y * sBatch + (size_t)blockIdx.x * 2048;
    u16* prow = PTb + blockIdx.y * pBatch + (size_t)blockIdx.x * 2048;
    const float2* sf = SF + (size_t)blockIdx.y * 2048;
    const int t = threadIdx.x;

    float4 v0 = *(const float4*)&row[4 * t];
    float4 v1 = *(const float4*)&row[1024 + 4 * t];
    float2 p0 = sf[4 * t], p1 = sf[4 * t + 1], p2 = sf[4 * t + 2], p3 = sf[4 * t + 3];
    float2 q0 = sf[1024 + 4 * t], q1 = sf[1024 + 4 * t + 1],
           q2 = sf[1024 + 4 * t + 2], q3 = sf[1024 + 4 * t + 3];

    ushort4 o0 = { f2bf(__expf(v0.x - p0.x) * p0.y),
                   f2bf(__expf(v0.y - p1.x) * p1.y),
                   f2bf(__expf(v0.z - p2.x) * p2.y),
                   f2bf(__expf(v0.w - p3.x) * p3.y) };
    ushort4 o1 = { f2bf(__expf(v1.x - q0.x) * q0.y),
                   f2bf(__expf(v1.y - q1.x) * q1.y),
                   f2bf(__expf(v1.z - q2.x) * q2.y),
                   f2bf(__expf(v1.w - q3.x) * q3.y) };
    *(ushort4*)&prow[4 * t] = o0;
    *(ushort4*)&prow[1024 + 4 * t] = o1;
}

// ---------------- driver ----------------
extern "C" void kernel_launch(void* const* d_in, const int* in_sizes, int n_in,
                              void* d_out, int out_size, void* d_ws, size_t ws_size,
                              hipStream_t stream)
{
    const size_t MB = 1048576;
    const size_t WREG = 34 * MB;
    const size_t PER  = 32 * MB;
    const size_t PER_US = PER / 2, PER_F = PER / 4;

    char* ws = (char*)d_ws;
    u16* WQT2 = (u16*)ws;
    u16* WKT2 = (u16*)(ws + 4 * MB);
    u16* M2   = (u16*)(ws + 8 * MB);
    u16* WObf = (u16*)(ws + 12 * MB);
    u16* WVT  = (u16*)(ws + 14 * MB);
    u16* WOV  = (u16*)(ws + 16 * MB);
    u16* xbf  = (u16*)(ws + 18 * MB);
    // softmax stats: band partials [G][16][2048] float2 = 1 MB at ws+0 (dead WQT2),
    // combined finals [G][2048] float2 = 64 KB at ws+1MB (still inside WQT2 region)
    float2* STATSG = (float2*)ws;
    float2* STATSF = (float2*)(ws + 1 * MB);

    int G = (ws_size >= WREG + 4 * PER) ? 4 : (ws_size >= WREG + 2 * PER) ? 2 : 1;

    const float* x = (const float*)d_in[0];
    float* out = (float*)d_out;
    dim3 blk(256);

    hipFuncSetAttribute((const void*)gemm_w<3, 0, 256, 256, 2, 4, 1>,
                        hipFuncAttributeMaxDynamicSharedMemorySize, 131072);
    hipFuncSetAttribute((const void*)gemm_w<3, 1, 256, 128, 4, 2, 0>,
                        hipFuncAttributeMaxDynamicSharedMemorySize, 98304);

    // ---- weight prep (once): fused elementwise + split-K GEMMs, merged reduce ----
    float* PART1 = (float*)(ws + WREG);            // 16 MB fp32 partials
    float* PART2 = (float*)(ws + WREG + 16 * MB);  // 16 MB fp32 partials
    wprep<<<dim3(32, 32, 4), blk, 0, stream>>>(
        (const float*)d_in[1], (const float*)d_in[2],
        (const float*)d_in[3], (const float*)d_in[4],
        WQT2, WKT2, WVT, WObf);
    gemm_big<3, 1><<<dim3(8, 8, 4), blk, 0, stream>>>(WKT2, 1048576, WQT2, 1048576,
                                                      PART1, 1048576, 1024, 1024, 1024);
    gemm_big<1, 1><<<dim3(8, 8, 4), blk, 0, stream>>>(WObf, 0, WVT, 0,
                                                      PART2, 1048576, 1024, 1024, 1024);
    reduce4b<<<dim3(1024, 2), blk, 0, stream>>>((const float4*)PART1, (const float4*)PART2,
                                                M2, WOV);

    for (int b0 = 0; b0 < 4; b0 += G) {
        char* R = ws + WREG;
        u16*   xT2 = (u16*)R;               // [i,d] 64x f16-split, plane 2097152 u16
        u16*   TT2 = (u16*)(R + 8 * MB);    // [j,d] split(T/64)
        float* ST  = (float*)(R + 16 * MB); // fp32 S^T [j,i]
        u16*   PTb = (u16*)(R + 8 * MB);    // bf16 P^T [j,i] (over dead TT2)
        u16*   XPT = (u16*)R;               // bf16 [j,d'] (over dead xT2)

        // x -> xbf (bf16 copy) + xT2 (transposed 64x f16 2-plane), one pass
        xprep<<<dim3(64, 32, G), blk, 0, stream>>>(x + (size_t)b0 * 2097152, 2097152,
                                                   xbf + (size_t)b0 * 2097152, 2097152,
                                                   xT2, PER_US, 2097152);
        // T^T = (64x)^T M: [j,d] f16-split out
        gemm_w<3, 1, 256, 128, 4, 2, 0><<<dim3(8, 8, G), 512, 98304, stream>>>(
            xT2, PER_US, 2097152, M2, 0, 1048576, TT2, PER_US, 2097152,
            2048, 1024, 1024, nullptr);
        // ST[j,i] = (T/64)[j,:] . (64x)[i,:]  (operand swap -> writes S^T)
        // + per-column softmax partials into STATSG
        gemm_w<3, 0, 256, 256, 2, 4, 1><<<dim3(8, 8, G), 512, 131072, stream>>>(
            TT2, PER_US, 2097152, xT2, PER_US, 2097152, ST, PER_F, 0,
            2048, 2048, 1024, STATSG);
        // combine 16 band partials -> final (M, 1/S) per column
        statsred<<<dim3(8, G), blk, 0, stream>>>(STATSG, STATSF);
        // PT[j,i] = bf16 softmax (fully parallel, one row per block)
        texp<<<dim3(2048, G), blk, 0, stream>>>(ST, PER_F, STATSF, PTb, PER_US);
        // XPT[j,d'] = PT[j,:] . xbf[d',:]  (XPT over dead xT2)
        gemm_w<1, 2, 256, 128, 4, 2, 0><<<dim3(8, 8, G), 512, 49152, stream>>>(
            PTb, PER_US, 0, xbf + (size_t)b0 * 2097152, 2097152, 0,
            XPT, PER_US, 0, 2048, 1024, 2048, nullptr);
        // out[d,j] = WOV[d,:] . XPT[j,:]
        gemm_w<1, 0, 256, 128, 4, 2, 0><<<dim3(16, 4, G), 512, 49152, stream>>>(
            WOV, 0, 0, XPT, PER_US, 0, out + (size_t)b0 * 2097152, 2097152, 0,
            1024, 2048, 1024, nullptr);
    }
}